// Round 2
// baseline (896.794 us; speedup 1.0000x reference)
//
#include <hip/hip_runtime.h>
#include <math.h>

#define NB 16384
#define LH 50
#define D  64

// 64 fp32 accumulators += xk * wrow[0..63], wrow wave-uniform (LDS broadcast
// or global->s_load). Guaranteed ds_read_b128 via float4.
__device__ __forceinline__ void mv_step(float* acc, float xk, const float* wrow) {
    const float4* w4 = (const float4*)wrow;
    #pragma unroll
    for (int d4 = 0; d4 < 16; ++d4) {
        float4 w = w4[d4];
        acc[4 * d4 + 0] = fmaf(xk, w.x, acc[4 * d4 + 0]);
        acc[4 * d4 + 1] = fmaf(xk, w.y, acc[4 * d4 + 1]);
        acc[4 * d4 + 2] = fmaf(xk, w.z, acc[4 * d4 + 2]);
        acc[4 * d4 + 3] = fmaf(xk, w.w, acc[4 * d4 + 3]);
    }
}

// One wave per node b; lane = history slot (50 of 64 active).
// Hot weights (w1, w2, wa1-lower) staged in 64 KB LDS -> broadcast ds_read_b128
// instead of scalar-cache-missing s_loads. 512-thr blocks, 2 blocks/CU.
__global__ __launch_bounds__(512, 4) void uv_agg_kernel(
    const int*   __restrict__ nodes,
    const int*   __restrict__ history_uv,
    const int*   __restrict__ history_r,
    const float* __restrict__ v2e,
    const float* __restrict__ u2e,
    const float* __restrict__ r2e,
    const float* __restrict__ w1,   // [128,64]
    const float* __restrict__ b1,   // [64]
    const float* __restrict__ w2,   // [64,64]
    const float* __restrict__ b2,   // [64]
    const float* __restrict__ wa1,  // [128,64]
    const float* __restrict__ ba1,  // [64]
    const float* __restrict__ wa2,  // [64,64]
    const float* __restrict__ ba2,  // [64]
    const float* __restrict__ wa3,  // [64]
    const float* __restrict__ ba3,  // [1]
    float*       __restrict__ out)  // [B,64]
{
    // 64 KB static LDS: w1 (8192 f) | w2 (4096 f) | wa1 rows 0..63 (4096 f)
    __shared__ float lds_w[16384];
    float* lw1  = lds_w;            // [128][64]
    float* lw2  = lds_w + 8192;     // [64][64]
    float* lwa1 = lds_w + 12288;    // [64][64]

    // cooperative stage: 16384 floats / 512 thr = 8 float4 per thread
    {
        const int tid = threadIdx.x;
        #pragma unroll
        for (int i = tid * 4; i < 16384; i += 512 * 4) {
            float4 v;
            if (i < 8192)       v = *(const float4*)(w1 + i);
            else if (i < 12288) v = *(const float4*)(w2 + (i - 8192));
            else                v = *(const float4*)(wa1 + (i - 12288));
            *(float4*)(lds_w + i) = v;
        }
    }
    __syncthreads();

    const int lane = threadIdx.x & 63;
    const int wid  = threadIdx.x >> 6;
    const int b    = blockIdx.x * 8 + wid;

    // ---- wave-uniform att1 half: c[lane] = ba1[lane] + sum_k u_k * wa1[64+k][lane]
    // u row is wave-uniform (s_load); wa1-upper read coalesced per k.
    float c_val;
    {
        const int node = nodes[b];
        const float* __restrict__ urow = u2e + (size_t)node * D;
        float c = ba1[lane];
        #pragma unroll 8
        for (int k = 0; k < D; ++k)
            c = fmaf(urow[k], wa1[(D + k) * D + lane], c);
        c_val = c;
    }

    // ---- per-lane token
    const bool act = lane < LH;
    const int iv = act ? history_uv[b * LH + lane] : 0;
    const int ir = act ? history_r [b * LH + lane] : 0;
    const float4* __restrict__ x4 = (const float4*)(v2e + (size_t)iv * D);
    const float4* __restrict__ r4 = (const float4*)(r2e + (size_t)ir * D);

    // ---- layer 1: h = relu(W1[0:64]^T e_uv + W1[64:128]^T e_r + b1)
    float h[D];
    #pragma unroll
    for (int d = 0; d < D; ++d) h[d] = b1[d];
    #pragma unroll 1
    for (int k4 = 0; k4 < 16; ++k4) {          // x from memory -> rolled loop ok
        float4 xv = x4[k4];
        mv_step(h, xv.x, lw1 + (4 * k4 + 0) * D);
        mv_step(h, xv.y, lw1 + (4 * k4 + 1) * D);
        mv_step(h, xv.z, lw1 + (4 * k4 + 2) * D);
        mv_step(h, xv.w, lw1 + (4 * k4 + 3) * D);
    }
    #pragma unroll 1
    for (int k4 = 0; k4 < 16; ++k4) {
        float4 xv = r4[k4];
        mv_step(h, xv.x, lw1 + (D + 4 * k4 + 0) * D);
        mv_step(h, xv.y, lw1 + (D + 4 * k4 + 1) * D);
        mv_step(h, xv.z, lw1 + (D + 4 * k4 + 2) * D);
        mv_step(h, xv.w, lw1 + (D + 4 * k4 + 3) * D);
    }
    #pragma unroll
    for (int d = 0; d < D; ++d) h[d] = fmaxf(h[d], 0.f);

    // ---- layer 2: o = relu(W2^T h + b2)   (h in regs -> full unroll)
    float o[D];
    #pragma unroll
    for (int d = 0; d < D; ++d) o[d] = b2[d];
    #pragma unroll
    for (int k = 0; k < D; ++k) mv_step(o, h[k], lw2 + k * D);
    #pragma unroll
    for (int d = 0; d < D; ++d) o[d] = fmaxf(o[d], 0.f);

    // ---- att1: a1 = relu(c + Wa1[0:64]^T o); c broadcast via shuffles
    float a1[D];
    #pragma unroll
    for (int d = 0; d < D; ++d) a1[d] = __shfl(c_val, d, 64);
    #pragma unroll
    for (int k = 0; k < D; ++k) mv_step(a1, o[k], lwa1 + k * D);
    #pragma unroll
    for (int d = 0; d < D; ++d) a1[d] = fmaxf(a1[d], 0.f);

    // ---- att2 (+relu) and att3 logit  (wa2 not staged: s_load path)
    float a2[D];
    #pragma unroll
    for (int d = 0; d < D; ++d) a2[d] = ba2[d];
    #pragma unroll
    for (int k = 0; k < D; ++k) mv_step(a2, a1[k], wa2 + k * D);
    float lg = ba3[0];
    #pragma unroll
    for (int d = 0; d < D; ++d) lg = fmaf(fmaxf(a2[d], 0.f), wa3[d], lg);
    if (!act) lg = -1e30f;

    // ---- softmax over history slots (wave-level)
    float m = lg;
    #pragma unroll
    for (int off = 32; off >= 1; off >>= 1)
        m = fmaxf(m, __shfl_xor(m, off, 64));
    const float e = __expf(lg - m);            // idle lanes: exp(-huge) = 0
    float s = e;
    #pragma unroll
    for (int off = 32; off >= 1; off >>= 1)
        s += __shfl_xor(s, off, 64);
    const float att = e / s;

    // ---- out[b,:] = sum_l att_l * o_l : 64-component butterfly reduction
    float r[D];
    #pragma unroll
    for (int d = 0; d < D; ++d) r[d] = att * o[d];
    #pragma unroll
    for (int off = 32; off >= 1; off >>= 1) {
        #pragma unroll
        for (int d = 0; d < D; ++d) r[d] += __shfl_xor(r[d], off, 64);
    }

    // every lane holds the full row; lane 0 writes 16 float4s
    if (lane == 0) {
        float4* orow = (float4*)(out + (size_t)b * D);
        #pragma unroll
        for (int d4 = 0; d4 < 16; ++d4)
            orow[d4] = make_float4(r[4 * d4 + 0], r[4 * d4 + 1],
                                   r[4 * d4 + 2], r[4 * d4 + 3]);
    }
}

extern "C" void kernel_launch(void* const* d_in, const int* in_sizes, int n_in,
                              void* d_out, int out_size, void* d_ws, size_t ws_size,
                              hipStream_t stream) {
    const int*   nodes      = (const int*)  d_in[0];
    const int*   history_uv = (const int*)  d_in[1];
    const int*   history_r  = (const int*)  d_in[2];
    const float* v2e        = (const float*)d_in[3];
    const float* u2e        = (const float*)d_in[4];
    const float* r2e        = (const float*)d_in[5];
    const float* w1         = (const float*)d_in[6];
    const float* b1         = (const float*)d_in[7];
    const float* w2         = (const float*)d_in[8];
    const float* b2         = (const float*)d_in[9];
    const float* wa1        = (const float*)d_in[10];
    const float* ba1        = (const float*)d_in[11];
    const float* wa2        = (const float*)d_in[12];
    const float* ba2        = (const float*)d_in[13];
    const float* wa3        = (const float*)d_in[14];
    const float* ba3        = (const float*)d_in[15];
    float* out = (float*)d_out;

    uv_agg_kernel<<<NB / 8, 512, 0, stream>>>(
        nodes, history_uv, history_r, v2e, u2e, r2e,
        w1, b1, w2, b2, wa1, ba1, wa2, ba2, wa3, ba3, out);
}

// Round 3
// 252.493 us; speedup vs baseline: 3.5518x; 3.5518x over previous
//
#include <hip/hip_runtime.h>
#include <math.h>

#define NB 16384
#define LH 50
#define D  64

typedef _Float16 half8  __attribute__((ext_vector_type(8)));
typedef float    f32x16 __attribute__((ext_vector_type(16)));

#define MFMA(a, b, c) __builtin_amdgcn_mfma_f32_32x32x16_f16((a), (b), (c), 0, 0, 0)

// A/B frag layouts (32x32x16): A[m][k]: m=lane&31, k=(lane>>5)*8+j (8 contiguous k)
// B[k][n]: n=lane&31, k=(lane>>5)*8+j
// C/D: col=lane&31, row=(reg&3)+8*(reg>>2)+4*(lane>>5)   [m74/m101 verified]

// convert 8 contiguous fp32 -> half8
__device__ __forceinline__ half8 cvt8(const float* __restrict__ p) {
    float4 u = *(const float4*)p;
    float4 v = *(const float4*)(p + 4);
    half8 r;
    r[0] = (_Float16)u.x; r[1] = (_Float16)u.y; r[2] = (_Float16)u.z; r[3] = (_Float16)u.w;
    r[4] = (_Float16)v.x; r[5] = (_Float16)v.y; r[6] = (_Float16)v.z; r[7] = (_Float16)v.w;
    return r;
}

// B-fragment gathered straight from a global [K][64] fp32 matrix
__device__ __forceinline__ half8 gfrag(const float* __restrict__ w, int nt, int ks, int lane) {
    const int k0 = ks * 16 + (lane >> 5) * 8;
    const int n  = nt * 32 + (lane & 31);
    const float* p = w + k0 * 64 + n;
    half8 r;
    #pragma unroll
    for (int j = 0; j < 8; ++j) r[j] = (_Float16)p[j * 64];
    return r;
}

// act-buffer addressing: halves, XOR swizzle keeps frag reads 16B-aligned and
// makes the C-layout scatter-writes <=2-way bank aliasing (free)
__device__ __forceinline__ int act_addr(int m, int k) {
    return m * 64 + (k ^ ((m & 7) * 8));
}

// relu + f16 + scatter one 32x32 C tile into the act buffer (C-layout -> [m][k])
__device__ __forceinline__ void scatter_tile(_Float16* __restrict__ lact,
                                             const f32x16& acc, int mt, int nt, int lane) {
    const int k     = nt * 32 + (lane & 31);
    const int mbase = mt * 32 + 4 * (lane >> 5);
    #pragma unroll
    for (int i = 0; i < 16; ++i) {
        const int m = mbase + (i & 3) + 8 * (i >> 2);
        lact[act_addr(m, k)] = (_Float16)fmaxf(acc[i], 0.f);
    }
}

// A-fragment read-back from act buffer
__device__ __forceinline__ half8 afrag(const _Float16* __restrict__ lact, int mt, int ks, int lane) {
    const int m  = mt * 32 + (lane & 31);
    const int k0 = ks * 16 + (lane >> 5) * 8;
    return *(const half8*)(lact + act_addr(m, k0));
}

__global__ __launch_bounds__(256, 2) void uv_agg_kernel(
    const int*   __restrict__ nodes,
    const int*   __restrict__ history_uv,
    const int*   __restrict__ history_r,
    const float* __restrict__ v2e,
    const float* __restrict__ u2e,
    const float* __restrict__ r2e,
    const float* __restrict__ w1,   // [128,64]
    const float* __restrict__ b1,
    const float* __restrict__ w2,   // [64,64]
    const float* __restrict__ b2,
    const float* __restrict__ wa1,  // [128,64] (rows 0..63: o-half, 64..127: u-half)
    const float* __restrict__ ba1,
    const float* __restrict__ wa2,  // [64,64]
    const float* __restrict__ ba2,
    const float* __restrict__ wa3,  // [64]
    const float* __restrict__ ba3,  // [1] (softmax-invariant -> unused)
    float*       __restrict__ out)  // [B,64]
{
    // 64 KB LDS (halves): w1 frags 8192 | w2 4096 | wa1low 4096 | 4x act 4096
    __shared__ _Float16 lds[32768];
    _Float16* lw1  = lds;
    _Float16* lw2  = lds + 8192;
    _Float16* lwa1 = lds + 12288;

    const int tid  = threadIdx.x;
    const int lane = tid & 63;
    const int wid  = tid >> 6;
    _Float16* lact = lds + 16384 + wid * 4096;

    // ---- stage w1 / w2 / wa1-low as f16 B-fragments (frag-linear, b128 writes)
    for (int i = tid; i < 2048; i += 256) {     // 2048 (frag,lane) pairs of 8 halves
        const float* src; int dsti; int f, ln;
        if (i < 1024)      { f = i >> 6;           ln = i & 63;
            const int nt = f >> 3, ks = f & 7;
            src  = w1  + (ks * 16 + (ln >> 5) * 8) * 64 + nt * 32 + (ln & 31);
            dsti = i * 8;
        } else if (i < 1536) { const int ii = i - 1024; f = ii >> 6; ln = ii & 63;
            const int nt = f >> 2, ks = f & 3;
            src  = w2  + (ks * 16 + (ln >> 5) * 8) * 64 + nt * 32 + (ln & 31);
            dsti = 8192 + ii * 8;
        } else              { const int ii = i - 1536; f = ii >> 6; ln = ii & 63;
            const int nt = f >> 2, ks = f & 3;
            src  = wa1 + (ks * 16 + (ln >> 5) * 8) * 64 + nt * 32 + (ln & 31);
            dsti = 12288 + ii * 8;
        }
        half8 v;
        #pragma unroll
        for (int j = 0; j < 8; ++j) v[j] = (_Float16)src[j * 64];
        *(half8*)(lds + dsti) = v;
    }
    __syncthreads();

    const int b    = blockIdx.x * 4 + wid;
    const int c31  = lane & 31;
    const int hv   = lane >> 5;

    // ---- wave-uniform att1 u-half: cu[d=lane] = ba1[d] + sum_k u[k]*wa1[64+k][d]
    float cu = ba1[lane];
    {
        const int node = nodes[b];                 // wave-uniform -> s_load path
        const float* __restrict__ urow = u2e + (size_t)node * D;
        #pragma unroll 8
        for (int k = 0; k < D; ++k)
            cu = fmaf(urow[k], wa1[(D + k) * D + lane], cu);
    }
    const float cunt0 = __shfl(cu, c31, 64);       // c[col], col = c31      (nt=0)
    const float cunt1 = __shfl(cu, 32 + c31, 64);  // c[32+col]              (nt=1)

    // ---- token indices (rows 50..63 clamp to 49; masked at softmax)
    const int m1c = min(32 + c31, LH - 1);
    const int iv0 = history_uv[b * LH + c31];
    const int iv1 = history_uv[b * LH + m1c];
    const int ir0 = history_r [b * LH + c31];
    const int ir1 = history_r [b * LH + m1c];
    const float* __restrict__ av0 = v2e + (size_t)iv0 * D + hv * 8;
    const float* __restrict__ av1 = v2e + (size_t)iv1 * D + hv * 8;
    const float* __restrict__ ar0 = r2e + (size_t)ir0 * D + hv * 8;
    const float* __restrict__ ar1 = r2e + (size_t)ir1 * D + hv * 8;

    // ---- layer 1: h = relu([e_uv | e_r] @ w1 + b1), A-frags straight from global
    f32x16 h00, h01, h10, h11;
    {
        const float b1lo = b1[c31], b1hi = b1[32 + c31];
        #pragma unroll
        for (int i = 0; i < 16; ++i) { h00[i] = b1lo; h01[i] = b1hi; h10[i] = b1lo; h11[i] = b1hi; }
    }
    #pragma unroll
    for (int ks = 0; ks < 8; ++ks) {
        const float* s0 = (ks < 4) ? (av0 + ks * 16) : (ar0 + (ks - 4) * 16);
        const float* s1 = (ks < 4) ? (av1 + ks * 16) : (ar1 + (ks - 4) * 16);
        half8 a0 = cvt8(s0);
        half8 a1 = cvt8(s1);
        half8 wlo = *(const half8*)(lw1 + (ks)     * 512 + lane * 8);   // nt=0
        half8 whi = *(const half8*)(lw1 + (8 + ks) * 512 + lane * 8);   // nt=1
        h00 = MFMA(a0, wlo, h00); h01 = MFMA(a0, whi, h01);
        h10 = MFMA(a1, wlo, h10); h11 = MFMA(a1, whi, h11);
    }
    scatter_tile(lact, h00, 0, 0, lane); scatter_tile(lact, h01, 0, 1, lane);
    scatter_tile(lact, h10, 1, 0, lane); scatter_tile(lact, h11, 1, 1, lane);

    // ---- layer 2: o = relu(h @ w2 + b2); o stays in fp32 regs for the epilogue
    f32x16 o00, o01, o10, o11;
    {
        const float b2lo = b2[c31], b2hi = b2[32 + c31];
        #pragma unroll
        for (int i = 0; i < 16; ++i) { o00[i] = b2lo; o01[i] = b2hi; o10[i] = b2lo; o11[i] = b2hi; }
    }
    #pragma unroll
    for (int ks = 0; ks < 4; ++ks) {
        half8 a0 = afrag(lact, 0, ks, lane);
        half8 a1 = afrag(lact, 1, ks, lane);
        half8 wlo = *(const half8*)(lw2 + (ks)     * 512 + lane * 8);
        half8 whi = *(const half8*)(lw2 + (4 + ks) * 512 + lane * 8);
        o00 = MFMA(a0, wlo, o00); o01 = MFMA(a0, whi, o01);
        o10 = MFMA(a1, wlo, o10); o11 = MFMA(a1, whi, o11);
    }
    #pragma unroll
    for (int i = 0; i < 16; ++i) {
        o00[i] = fmaxf(o00[i], 0.f); o01[i] = fmaxf(o01[i], 0.f);
        o10[i] = fmaxf(o10[i], 0.f); o11[i] = fmaxf(o11[i], 0.f);
    }
    scatter_tile(lact, o00, 0, 0, lane); scatter_tile(lact, o01, 0, 1, lane);
    scatter_tile(lact, o10, 1, 0, lane); scatter_tile(lact, o11, 1, 1, lane);

    // ---- att1: a1 = relu(o @ wa1_low + (ba1 + u-half))  (u-half folded into init)
    f32x16 s00, s01, s10, s11;
    #pragma unroll
    for (int i = 0; i < 16; ++i) { s00[i] = cunt0; s01[i] = cunt1; s10[i] = cunt0; s11[i] = cunt1; }
    #pragma unroll
    for (int ks = 0; ks < 4; ++ks) {
        half8 a0 = afrag(lact, 0, ks, lane);
        half8 a1 = afrag(lact, 1, ks, lane);
        half8 wlo = *(const half8*)(lwa1 + (ks)     * 512 + lane * 8);
        half8 whi = *(const half8*)(lwa1 + (4 + ks) * 512 + lane * 8);
        s00 = MFMA(a0, wlo, s00); s01 = MFMA(a0, whi, s01);
        s10 = MFMA(a1, wlo, s10); s11 = MFMA(a1, whi, s11);
    }
    scatter_tile(lact, s00, 0, 0, lane); scatter_tile(lact, s01, 0, 1, lane);
    scatter_tile(lact, s10, 1, 0, lane); scatter_tile(lact, s11, 1, 1, lane);

    // ---- att2: a2 = a1relu @ wa2 + ba2   (wa2 B-frags from global, L1-hot)
    f32x16 t00, t01, t10, t11;
    {
        const float blo = ba2[c31], bhi = ba2[32 + c31];
        #pragma unroll
        for (int i = 0; i < 16; ++i) { t00[i] = blo; t01[i] = bhi; t10[i] = blo; t11[i] = bhi; }
    }
    #pragma unroll
    for (int ks = 0; ks < 4; ++ks) {
        half8 a0 = afrag(lact, 0, ks, lane);
        half8 a1 = afrag(lact, 1, ks, lane);
        half8 wlo = gfrag(wa2, 0, ks, lane);
        half8 whi = gfrag(wa2, 1, ks, lane);
        t00 = MFMA(a0, wlo, t00); t01 = MFMA(a0, whi, t01);
        t10 = MFMA(a1, wlo, t10); t11 = MFMA(a1, whi, t11);
    }

    // ---- logits: lg[m] = sum_n relu(a2[m][n]) * wa3[n]  (ba3 softmax-invariant)
    // per-lane partials for its 32 (mt,i) rows, then butterfly over the 32 cols
    float p[32];
    {
        const float w3lo = wa3[c31], w3hi = wa3[32 + c31];
        #pragma unroll
        for (int i = 0; i < 16; ++i) {
            p[i]      = fmaxf(t00[i], 0.f) * w3lo + fmaxf(t01[i], 0.f) * w3hi;
            p[16 + i] = fmaxf(t10[i], 0.f) * w3lo + fmaxf(t11[i], 0.f) * w3hi;
        }
    }
    #pragma unroll
    for (int off = 1; off <= 16; off <<= 1) {
        #pragma unroll
        for (int j = 0; j < 32; ++j) p[j] += __shfl_xor(p[j], off, 64);
    }

    // ---- softmax over rows < 50 (rows this lane holds: +4*hv pattern)
    const int rbase = 4 * hv;
    float mx = -1e30f;
    #pragma unroll
    for (int j = 0; j < 32; ++j) {
        const int i = j & 15;
        const int r = (j >> 4) * 32 + (i & 3) + 8 * (i >> 2) + rbase;
        if (r < LH) mx = fmaxf(mx, p[j]);
    }
    mx = fmaxf(mx, __shfl_xor(mx, 32, 64));
    float ssum = 0.f;
    #pragma unroll
    for (int j = 0; j < 32; ++j) {
        const int i = j & 15;
        const int r = (j >> 4) * 32 + (i & 3) + 8 * (i >> 2) + rbase;
        p[j] = (r < LH) ? __expf(p[j] - mx) : 0.f;
        ssum += p[j];
    }
    ssum += __shfl_xor(ssum, 32, 64);
    const float inv = 1.f / ssum;

    // ---- out[d] = sum_m att[m] * o[m][d] ; lane's att rows == lane's o rows
    float p0 = 0.f, p1 = 0.f;
    #pragma unroll
    for (int i = 0; i < 16; ++i) {
        const float a0 = p[i] * inv;        // mt=0 rows
        const float a1 = p[16 + i] * inv;   // mt=1 rows
        p0 = fmaf(a0, o00[i], p0); p1 = fmaf(a0, o01[i], p1);
        p0 = fmaf(a1, o10[i], p0); p1 = fmaf(a1, o11[i], p1);
    }
    p0 += __shfl_xor(p0, 32, 64);           // combine row-halves per column
    p1 += __shfl_xor(p1, 32, 64);
    out[(size_t)b * D + lane] = hv ? p1 : p0;   // d = lane = (hv?32:0)+c31
}

extern "C" void kernel_launch(void* const* d_in, const int* in_sizes, int n_in,
                              void* d_out, int out_size, void* d_ws, size_t ws_size,
                              hipStream_t stream) {
    const int*   nodes      = (const int*)  d_in[0];
    const int*   history_uv = (const int*)  d_in[1];
    const int*   history_r  = (const int*)  d_in[2];
    const float* v2e        = (const float*)d_in[3];
    const float* u2e        = (const float*)d_in[4];
    const float* r2e        = (const float*)d_in[5];
    const float* w1         = (const float*)d_in[6];
    const float* b1         = (const float*)d_in[7];
    const float* w2         = (const float*)d_in[8];
    const float* b2         = (const float*)d_in[9];
    const float* wa1        = (const float*)d_in[10];
    const float* ba1        = (const float*)d_in[11];
    const float* wa2        = (const float*)d_in[12];
    const float* ba2        = (const float*)d_in[13];
    const float* wa3        = (const float*)d_in[14];
    const float* ba3        = (const float*)d_in[15];
    float* out = (float*)d_out;

    uv_agg_kernel<<<NB / 4, 256, 0, stream>>>(
        nodes, history_uv, history_r, v2e, u2e, r2e,
        w1, b1, w2, b2, wa1, ba1, wa2, ba2, wa3, ba3, out);
}

// Round 4
// 228.795 us; speedup vs baseline: 3.9196x; 1.1036x over previous
//
#include <hip/hip_runtime.h>
#include <math.h>

#define NB 16384
#define LH 50
#define D  64

typedef _Float16 half2v __attribute__((ext_vector_type(2)));
typedef _Float16 half8  __attribute__((ext_vector_type(8)));
typedef float    f32x16 __attribute__((ext_vector_type(16)));
typedef unsigned int u32;

#define MFMA(a, b, c) __builtin_amdgcn_mfma_f32_32x32x16_f16((a), (b), (c), 0, 0, 0)

// ---- fragment facts (32x32x16, verified m74/m101 + R3 pass) ----
// A[m][k]: m=lane&31, k=(lane>>5)*8+j (8 contiguous k per lane)
// B[k][n]: n=lane&31, k=(lane>>5)*8+j
// C/D:     col=lane&31, row=(reg&3)+8*(reg>>2)+4*(lane>>5)

__device__ __forceinline__ u32 pack2(float a, float b) {
    half2v h; h[0] = (_Float16)a; h[1] = (_Float16)b;
    return __builtin_bit_cast(u32, h);
}
__device__ __forceinline__ half8 mk8(u32 a, u32 b, u32 c, u32 d) {
    uint4 t = make_uint4(a, b, c, d);
    return __builtin_bit_cast(half8, t);
}
__device__ __forceinline__ half8 cvt8(const float* __restrict__ p) {
    float4 u = *(const float4*)p;
    float4 v = *(const float4*)(p + 4);
    return mk8(pack2(u.x, u.y), pack2(u.z, u.w), pack2(v.x, v.y), pack2(v.z, v.w));
}

// relu + f16-pack + lane^32 exchange: one C tile -> two B-frags (k-halves) for
// the NEXT transposed GEMM (contraction over this tile's 32 rows).
__device__ __forceinline__ void xform_tile(const f32x16& t, int hv, half8& f0, half8& f1) {
    u32 p[8], rp[8];
    #pragma unroll
    for (int q = 0; q < 8; ++q) p[q] = pack2(fmaxf(t[2*q], 0.f), fmaxf(t[2*q+1], 0.f));
    #pragma unroll
    for (int q = 0; q < 8; ++q) rp[q] = (u32)__shfl_xor((int)p[q], 32, 64);
    f0 = hv ? mk8(rp[2], rp[3], p[2], p[3]) : mk8(p[0], p[1], rp[0], rp[1]);
    f1 = hv ? mk8(rp[6], rp[7], p[6], p[7]) : mk8(p[4], p[5], rp[4], rp[5]);
}

// init both nt-tiles of one mt row-tile from a permuted bias table
__device__ __forceinline__ void initacc(f32x16& a0, f32x16& a1,
                                        const float4* __restrict__ tb4, int hv, int mt) {
    #pragma unroll
    for (int q = 0; q < 4; ++q) {
        float4 v = tb4[hv*8 + mt*4 + q];
        a0[4*q] = v.x; a0[4*q+1] = v.y; a0[4*q+2] = v.z; a0[4*q+3] = v.w;
        a1[4*q] = v.x; a1[4*q+1] = v.y; a1[4*q+2] = v.z; a1[4*q+3] = v.w;
    }
}

// ================= K1: weight/bias reorder into ws =================
// ws halves: w1f[2][8][64][8] | w2f[2][4][64][8] | wa1lowf | wa1upf | wa2f
// then f32 @ byte 49152: b1p[64] b2p[64] ba1p[64] ba2p[64] wa3p[64]
__global__ void uv_prep(const float* __restrict__ w1, const float* __restrict__ w2,
                        const float* __restrict__ wa1, const float* __restrict__ wa2,
                        const float* __restrict__ b1, const float* __restrict__ b2,
                        const float* __restrict__ ba1, const float* __restrict__ ba2,
                        const float* __restrict__ wa3,
                        _Float16* __restrict__ wsh, float* __restrict__ tbf) {
    const int idx = blockIdx.x * 256 + threadIdx.x;   // grid 96 -> idx < 24576
    const int j = idx & 7, lane = (idx >> 3) & 63;
    const int hv = lane >> 5, m31 = lane & 31;
    float v;
    if (idx < 8192)       { const int ks = (idx >> 9) & 7, mt = (idx >> 12) & 1;
        v = w1 [(ks*16 + hv*8 + j)*64 + mt*32 + m31]; }
    else if (idx < 12288) { const int ks = (idx >> 9) & 3, mt = (idx >> 11) & 1;
        v = w2 [(ks*16 + hv*8 + j)*64 + mt*32 + m31]; }
    else if (idx < 16384) { const int ks = (idx >> 9) & 3, mt = (idx >> 11) & 1;
        v = wa1[(ks*16 + hv*8 + j)*64 + mt*32 + m31]; }
    else if (idx < 20480) { const int ks = (idx >> 9) & 3, mt = (idx >> 11) & 1;
        v = wa1[(64 + ks*16 + hv*8 + j)*64 + mt*32 + m31]; }
    else                  { const int ks = (idx >> 9) & 3, mt = (idx >> 11) & 1;
        v = wa2[(ks*16 + hv*8 + j)*64 + mt*32 + m31]; }
    wsh[idx] = (_Float16)v;

    if (blockIdx.x == 0 && threadIdx.x < 64) {
        const int t = threadIdx.x;
        const int thv = t >> 5, r = t & 31, mt = r >> 4, i = r & 15;
        const int feat = mt*32 + (i & 3) + 8*(i >> 2) + 4*thv;
        tbf[t]       = b1[feat];
        tbf[64 + t]  = b2[feat];
        tbf[128 + t] = ba1[feat];
        tbf[192 + t] = ba2[feat];
        tbf[256 + t] = wa3[feat];
    }
}

// ================= K2: fused forward, one wave per node =================
__global__ __launch_bounds__(256) void uv_main(
    const int*   __restrict__ nodes,
    const int*   __restrict__ huv,
    const int*   __restrict__ hr,
    const float* __restrict__ v2e,
    const float* __restrict__ u2e,
    const float* __restrict__ r2e,
    const _Float16* __restrict__ wsh,
    const float* __restrict__ tbf,
    float*       __restrict__ out) {
    // stage 40 KB of A-frags (w1,w2,wa1low,wa1up) by straight b128 copy
    __shared__ uint4 lds4[2560];
    const int tid = threadIdx.x;
    for (int i = tid; i < 2560; i += 256) lds4[i] = ((const uint4*)wsh)[i];
    __syncthreads();
    const _Float16* lw = (const _Float16*)lds4;

    const int lane = tid & 63, wid = tid >> 6;
    const int b = blockIdx.x * 4 + wid;
    const int n = lane & 31, hv = lane >> 5;

    // ---- token rows (tok = nt*32+n; rows 50..63 duplicate row 49, masked later)
    const int t1  = (32 + n < LH) ? 32 + n : LH - 1;
    const int iv0 = huv[b*LH + n], iv1 = huv[b*LH + t1];
    const int ir0 = hr [b*LH + n], ir1 = hr [b*LH + t1];
    const float* xv0 = v2e + (size_t)iv0 * D + hv*8;
    const float* xv1 = v2e + (size_t)iv1 * D + hv*8;
    const float* xr0 = r2e + (size_t)ir0 * D + hv*8;
    const float* xr1 = r2e + (size_t)ir1 * D + hv*8;

    // ---- u-broadcast B-frags for att1's K-extension (u row wave-uniform)
    const float* urow = u2e + (size_t)nodes[b] * D + hv*8;
    half8 uf[4];
    #pragma unroll
    for (int ks = 0; ks < 4; ++ks) uf[ks] = cvt8(urow + ks*16);

    // ======== layer 1 (transposed): H[feat][tok] = W1^T @ X^T + b1
    f32x16 a00, a01, a10, a11;
    initacc(a00, a01, (const float4*)tbf, hv, 0);
    initacc(a10, a11, (const float4*)tbf, hv, 1);
    #pragma unroll
    for (int ks = 0; ks < 8; ++ks) {
        const float* p0 = (ks < 4) ? xv0 + ks*16 : xr0 + (ks - 4)*16;
        const float* p1 = (ks < 4) ? xv1 + ks*16 : xr1 + (ks - 4)*16;
        half8 bf0 = cvt8(p0), bf1 = cvt8(p1);
        half8 w0 = *(const half8*)(lw + ((0*8 + ks)*64 + lane)*8);
        half8 w1f = *(const half8*)(lw + ((1*8 + ks)*64 + lane)*8);
        a00 = MFMA(w0, bf0, a00);  a01 = MFMA(w0, bf1, a01);
        a10 = MFMA(w1f, bf0, a10); a11 = MFMA(w1f, bf1, a11);
    }
    half8 hf[2][4];                          // relu+exchange -> B-frags of H
    xform_tile(a00, hv, hf[0][0], hf[0][1]); xform_tile(a01, hv, hf[1][0], hf[1][1]);
    xform_tile(a10, hv, hf[0][2], hf[0][3]); xform_tile(a11, hv, hf[1][2], hf[1][3]);

    // ======== layer 2: O[feat][tok] = W2^T @ H + b2
    initacc(a00, a01, (const float4*)(tbf + 64), hv, 0);
    initacc(a10, a11, (const float4*)(tbf + 64), hv, 1);
    #pragma unroll
    for (int ks = 0; ks < 4; ++ks) {
        half8 w0 = *(const half8*)(lw + 8192 + ((0*4 + ks)*64 + lane)*8);
        half8 w1f = *(const half8*)(lw + 8192 + ((1*4 + ks)*64 + lane)*8);
        a00 = MFMA(w0, hf[0][ks], a00);  a01 = MFMA(w0, hf[1][ks], a01);
        a10 = MFMA(w1f, hf[0][ks], a10); a11 = MFMA(w1f, hf[1][ks], a11);
    }
    half8 of[2][4];                          // O frags: feed att1 AND the epilogue
    xform_tile(a00, hv, of[0][0], of[0][1]); xform_tile(a01, hv, of[1][0], of[1][1]);
    xform_tile(a10, hv, of[0][2], of[0][3]); xform_tile(a11, hv, of[1][2], of[1][3]);

    // ======== att1: A1 = relu(Wa1low^T @ O + Wa1up^T @ u_bcast + ba1)
    initacc(a00, a01, (const float4*)(tbf + 128), hv, 0);
    initacc(a10, a11, (const float4*)(tbf + 128), hv, 1);
    #pragma unroll
    for (int ks = 0; ks < 4; ++ks) {
        half8 w0 = *(const half8*)(lw + 12288 + ((0*4 + ks)*64 + lane)*8);
        half8 w1f = *(const half8*)(lw + 12288 + ((1*4 + ks)*64 + lane)*8);
        a00 = MFMA(w0, of[0][ks], a00);  a01 = MFMA(w0, of[1][ks], a01);
        a10 = MFMA(w1f, of[0][ks], a10); a11 = MFMA(w1f, of[1][ks], a11);
    }
    #pragma unroll
    for (int ks = 0; ks < 4; ++ks) {         // u K-extension (same B for both nt)
        half8 w0 = *(const half8*)(lw + 16384 + ((0*4 + ks)*64 + lane)*8);
        half8 w1f = *(const half8*)(lw + 16384 + ((1*4 + ks)*64 + lane)*8);
        a00 = MFMA(w0, uf[ks], a00);  a01 = MFMA(w0, uf[ks], a01);
        a10 = MFMA(w1f, uf[ks], a10); a11 = MFMA(w1f, uf[ks], a11);
    }
    half8 af[2][4];
    xform_tile(a00, hv, af[0][0], af[0][1]); xform_tile(a01, hv, af[1][0], af[1][1]);
    xform_tile(a10, hv, af[0][2], af[0][3]); xform_tile(a11, hv, af[1][2], af[1][3]);

    // ======== att2 + logits (wa2 A-frags from ws/global, L2-hot; mt sequential)
    const half8* wa2g = (const half8*)(wsh + 20480 * 1);  // frag-linear half8s
    float lg0 = 0.f, lg1 = 0.f;
    #pragma unroll
    for (int mt = 0; mt < 2; ++mt) {
        f32x16 c0, c1;
        initacc(c0, c1, (const float4*)(tbf + 192), hv, mt);
        #pragma unroll
        for (int ks = 0; ks < 4; ++ks) {
            half8 w = wa2g[(mt*4 + ks)*64 + lane];
            c0 = MFMA(w, af[0][ks], c0);
            c1 = MFMA(w, af[1][ks], c1);
        }
        #pragma unroll
        for (int q = 0; q < 4; ++q) {
            float4 w3 = ((const float4*)(tbf + 256))[hv*8 + mt*4 + q];
            lg0 += fmaxf(c0[4*q], 0.f)*w3.x + fmaxf(c0[4*q+1], 0.f)*w3.y
                 + fmaxf(c0[4*q+2], 0.f)*w3.z + fmaxf(c0[4*q+3], 0.f)*w3.w;
            lg1 += fmaxf(c1[4*q], 0.f)*w3.x + fmaxf(c1[4*q+1], 0.f)*w3.y
                 + fmaxf(c1[4*q+2], 0.f)*w3.z + fmaxf(c1[4*q+3], 0.f)*w3.w;
        }
    }
    // combine feat-halves across lane^32: each lane now holds logits of tokens n, n+32
    lg0 += __shfl_xor(lg0, 32, 64);
    lg1 += __shfl_xor(lg1, 32, 64);
    if (32 + n >= LH) lg1 = -1e30f;

    // ---- softmax over 64 tokens (butterfly over the 32 token-lanes)
    float mx = fmaxf(lg0, lg1);
    #pragma unroll
    for (int off = 16; off >= 1; off >>= 1) mx = fmaxf(mx, __shfl_xor(mx, off, 64));
    const float e0 = __expf(lg0 - mx);
    const float e1 = __expf(lg1 - mx);       // masked token: exp(-huge)=0
    float s = e0 + e1;
    #pragma unroll
    for (int off = 16; off >= 1; off >>= 1) s += __shfl_xor(s, off, 64);
    const float at0 = e0 / s, at1 = e1 / s;

    // ======== epilogue: out[feat] = sum_tok att[tok]*O[feat][tok]
    // per-lane weighted partials over its 2 tokens x 32 feats (from O frags)
    float cur[32];
    #pragma unroll
    for (int ks = 0; ks < 4; ++ks)
        #pragma unroll
        for (int j = 0; j < 8; ++j)
            cur[ks*8 + j] = at0 * (float)of[0][ks][j] + at1 * (float)of[1][ks][j];
    // recursive-halving reduce-scatter over the 32 token-lanes (5 levels, 31 shfl)
    #pragma unroll
    for (int k = 0; k < 5; ++k) {
        const int d = 1 << k, mybit = (lane >> k) & 1, half = 16 >> k;
        #pragma unroll
        for (int j2 = 0; j2 < 16; ++j2) {
            if (j2 < half) {
                float sel  = mybit ? cur[2*j2]     : cur[2*j2 + 1];
                float got  = __shfl_xor(sel, d, 64);
                float keep = mybit ? cur[2*j2 + 1] : cur[2*j2];
                cur[j2] = keep + got;
            }
        }
    }
    // lane owns feat = [bits: lane4 lane3 | hv | lane2 lane1 lane0]
    const int feat = ((lane >> 3) & 3)*16 + hv*8 + (lane & 7);
    out[(size_t)b * D + feat] = cur[0];
}

extern "C" void kernel_launch(void* const* d_in, const int* in_sizes, int n_in,
                              void* d_out, int out_size, void* d_ws, size_t ws_size,
                              hipStream_t stream) {
    const int*   nodes      = (const int*)  d_in[0];
    const int*   history_uv = (const int*)  d_in[1];
    const int*   history_r  = (const int*)  d_in[2];
    const float* v2e        = (const float*)d_in[3];
    const float* u2e        = (const float*)d_in[4];
    const float* r2e        = (const float*)d_in[5];
    const float* w1         = (const float*)d_in[6];
    const float* b1         = (const float*)d_in[7];
    const float* w2         = (const float*)d_in[8];
    const float* b2         = (const float*)d_in[9];
    const float* wa1        = (const float*)d_in[10];
    const float* ba1        = (const float*)d_in[11];
    const float* wa2        = (const float*)d_in[12];
    const float* ba2        = (const float*)d_in[13];
    const float* wa3        = (const float*)d_in[14];
    float* out = (float*)d_out;

    _Float16* wsh = (_Float16*)d_ws;
    float*    tbf = (float*)((char*)d_ws + 49152);

    uv_prep<<<96, 256, 0, stream>>>(w1, w2, wa1, wa2, b1, b2, ba1, ba2, wa3, wsh, tbf);
    uv_main<<<NB / 4, 256, 0, stream>>>(nodes, history_uv, history_r,
                                        v2e, u2e, r2e, wsh, tbf, out);
}